// Round 1
// 913.705 us; speedup vs baseline: 1.1612x; 1.1612x over previous
//
#include <hip/hip_runtime.h>

// MultiHeadAttention_Discrete — round 3.
// attn v3: QK^T moved to MFMA via fp16 hi/lo split (s = Hh·Bh + Hh·Bl + Hl·Bh,
//          |err| ~ 3e-6 == fp32-equivalent). Stats/candidates/gather/pass2
//          logic identical to v2, only the s-producer changed.
// ws layout (floats): Q[16*2048*64] | V[16*2048*64] | att[16*2048*64] | gs[2*2048*512]
// Qh/Ql (fp16, 4MB each) alias the gs region (gs written later by tubes).

#define NHEAD 8
#define NBATCH 2
#define SEQL 2048
#define BHN 16
#define TEMPF 0.006737946999085467f
#define CCAP 128

typedef __attribute__((ext_vector_type(8))) _Float16 half8;
typedef __attribute__((ext_vector_type(4))) _Float16 half4;
typedef __attribute__((ext_vector_type(4))) float f32x4;

__device__ __forceinline__ float gumbelf(float u) {
  return -__logf(-__logf(u + 1e-10f) + 1e-10f);
}
__device__ __forceinline__ float bmax16(float v) {
  v = fmaxf(v, __shfl_xor(v, 1));
  v = fmaxf(v, __shfl_xor(v, 2));
  v = fmaxf(v, __shfl_xor(v, 4));
  v = fmaxf(v, __shfl_xor(v, 8));
  return v;
}
__device__ __forceinline__ float bsum16(float v) {
  v += __shfl_xor(v, 1);
  v += __shfl_xor(v, 2);
  v += __shfl_xor(v, 4);
  v += __shfl_xor(v, 8);
  return v;
}

// Y[m][c] = sum_k X[m][k]*W[c][k] + bias[c];  M=4096, N=512, K=512.
__global__ __launch_bounds__(256) void gemm512(const float* __restrict__ X,
    const float* __restrict__ W, const float* __restrict__ bias,
    float* __restrict__ Y, int headsplit)
{
  __shared__ float Xt[64][68];
  __shared__ float WT[64][68];
  const int tid = threadIdx.x;
  const int tx = tid & 15, ty = tid >> 4;
  const int mt = blockIdx.x >> 3, nt = blockIdx.x & 7;
  const int m0 = mt << 6, n0 = nt << 6;
  float acc[4][4] = {};
  for (int kc = 0; kc < 8; ++kc) {
    if (kc) __syncthreads();
#pragma unroll
    for (int i = 0; i < 4; ++i) {
      const int f = (tid << 2) + i;
      const int r = f >> 4, k4 = (f & 15) << 2;
      *(float4*)&Xt[r][k4] = *(const float4*)&X[(size_t)(m0 + r) * 512 + (kc << 6) + k4];
      float4 w = *(const float4*)&W[(size_t)(n0 + r) * 512 + (kc << 6) + k4];
      WT[k4 + 0][r] = w.x; WT[k4 + 1][r] = w.y; WT[k4 + 2][r] = w.z; WT[k4 + 3][r] = w.w;
    }
    __syncthreads();
#pragma unroll 4
    for (int k4 = 0; k4 < 64; k4 += 4) {
      float4 A0 = *(const float4*)&Xt[(ty << 2) + 0][k4];
      float4 A1 = *(const float4*)&Xt[(ty << 2) + 1][k4];
      float4 A2 = *(const float4*)&Xt[(ty << 2) + 2][k4];
      float4 A3 = *(const float4*)&Xt[(ty << 2) + 3][k4];
      float4 B0 = *(const float4*)&WT[k4 + 0][tx << 2];
      float4 B1 = *(const float4*)&WT[k4 + 1][tx << 2];
      float4 B2 = *(const float4*)&WT[k4 + 2][tx << 2];
      float4 B3 = *(const float4*)&WT[k4 + 3][tx << 2];
      const float a[4][4] = {{A0.x,A0.y,A0.z,A0.w},{A1.x,A1.y,A1.z,A1.w},
                             {A2.x,A2.y,A2.z,A2.w},{A3.x,A3.y,A3.z,A3.w}};
      const float b[4][4] = {{B0.x,B0.y,B0.z,B0.w},{B1.x,B1.y,B1.z,B1.w},
                             {B2.x,B2.y,B2.z,B2.w},{B3.x,B3.y,B3.z,B3.w}};
#pragma unroll
      for (int i = 0; i < 4; ++i)
#pragma unroll
        for (int j = 0; j < 4; ++j)
          acc[i][j] += a[i][0]*b[0][j] + a[i][1]*b[1][j] + a[i][2]*b[2][j] + a[i][3]*b[3][j];
    }
  }
  const int c0 = n0 + (tx << 2);
  const float4 bv = *(const float4*)&bias[c0];
#pragma unroll
  for (int i = 0; i < 4; ++i) {
    const int m = m0 + (ty << 2) + i;
    float4 o = make_float4(acc[i][0] + bv.x, acc[i][1] + bv.y,
                           acc[i][2] + bv.z, acc[i][3] + bv.w);
    if (headsplit) {
      const int bb = m >> 11, s = m & 2047;
      *(float4*)&Y[(((size_t)(nt * NBATCH + bb) * SEQL + s) << 6) + (tx << 2)] = o;
    } else {
      *(float4*)&Y[((size_t)m << 9) + c0] = o;
    }
  }
}

// Split fp32 Q into fp16 hi + lo halves (x = hi + lo to ~2^-22 rel).
__global__ __launch_bounds__(256) void qsplit(const float* __restrict__ Q,
    _Float16* __restrict__ Qh, _Float16* __restrict__ Ql)
{
  const size_t i = ((size_t)blockIdx.x * 256 + threadIdx.x) << 2;
  const float4 x = *(const float4*)&Q[i];
  half4 h, l;
  h[0] = (_Float16)x.x; l[0] = (_Float16)(x.x - (float)h[0]);
  h[1] = (_Float16)x.y; l[1] = (_Float16)(x.y - (float)h[1]);
  h[2] = (_Float16)x.z; l[2] = (_Float16)(x.z - (float)h[2]);
  h[3] = (_Float16)x.w; l[3] = (_Float16)(x.w - (float)h[3]);
  *(half4*)&Qh[i] = h;
  *(half4*)&Ql[i] = l;
}

// Stage a 64-row x 64-col fp16 hi/lo tile into LDS with 16B-block XOR swizzle
// (blk ^= row&7) so B/A-fragment ds_read_b128 is 2-way (free) instead of 16-way.
__device__ __forceinline__ void stage_tile(const _Float16* __restrict__ Qh,
    const _Float16* __restrict__ Ql, _Float16* JH, _Float16* JL,
    size_t qrow0, int tid)
{
#pragma unroll
  for (int r = 0; r < 2; ++r) {
    const int idx = (r << 8) + tid;
    const int srow = idx >> 3, sblk = idx & 7;
    const int dst = (srow << 6) + (((sblk ^ srow) & 7) << 3);
    const size_t src = ((qrow0 + srow) << 6) + (sblk << 3);
    *(float4*)&JH[dst] = *(const float4*)&Qh[src];
    *(float4*)&JL[dst] = *(const float4*)&Ql[src];
  }
}

// 16 rows (this wave) x 64 cols QK^T tile via fp16x2-split MFMA.
// acc[ct][e]: col = ct*16 + (lane&15), row = 16*w + 4*(lane>>4) + e.
__device__ __forceinline__ void qk_tile(const _Float16* JH, const _Float16* JL,
    const half8 aH[2], const half8 aL[2], int lw, int lh, f32x4 acc[4])
{
#pragma unroll
  for (int ct = 0; ct < 4; ++ct) acc[ct] = (f32x4){0.f, 0.f, 0.f, 0.f};
#pragma unroll
  for (int ks = 0; ks < 2; ++ks) {
    half8 bh8[4], bl8[4];
#pragma unroll
    for (int ct = 0; ct < 4; ++ct) {
      const int jrow = (ct << 4) + lw;
      const int blk = (ks << 2) + lh;
      const int off = (jrow << 6) + (((blk ^ jrow) & 7) << 3);
      bh8[ct] = *(const half8*)&JH[off];
      bl8[ct] = *(const half8*)&JL[off];
    }
#pragma unroll
    for (int ct = 0; ct < 4; ++ct)
      acc[ct] = __builtin_amdgcn_mfma_f32_16x16x32_f16(aH[ks], bh8[ct], acc[ct], 0, 0, 0);
#pragma unroll
    for (int ct = 0; ct < 4; ++ct)
      acc[ct] = __builtin_amdgcn_mfma_f32_16x16x32_f16(aH[ks], bl8[ct], acc[ct], 0, 0, 0);
#pragma unroll
    for (int ct = 0; ct < 4; ++ct)
      acc[ct] = __builtin_amdgcn_mfma_f32_16x16x32_f16(aL[ks], bh8[ct], acc[ct], 0, 0, 0);
  }
}

// Fused attention v3 (MFMA QK^T; see header comment).
__global__ __launch_bounds__(256) void attn_fused(const float* __restrict__ Qf,
    const _Float16* __restrict__ Qh, const _Float16* __restrict__ Ql,
    const float* __restrict__ V, const float* __restrict__ U,
    float* __restrict__ logp, float* __restrict__ att)
{
  __shared__ __align__(16) _Float16 JH[4096];
  __shared__ __align__(16) _Float16 JL[4096];
  __shared__ unsigned short cand[64][CCAP];
  __shared__ int ccnt[64];
  const int tid = threadIdx.x;
  const int w = tid >> 6;
  const int l = tid & 63;
  const int lw = l & 15, lh = l >> 4;
  const int bh = ((blockIdx.x & 7) << 1) | ((blockIdx.x >> 3) & 1);
  const int rb = blockIdx.x >> 4;
  const int r0 = rb << 6;
  const size_t qb = (size_t)bh * SEQL;
  if (tid < 64) ccnt[tid] = 0;

  // ---- load Qi tile, pull this wave's A-fragments (rows 16w..16w+15) ----
  stage_tile(Qh, Ql, JH, JL, qb + r0, tid);
  __syncthreads();
  half8 aH[2], aL[2];
  const int arow = (w << 4) + lw;
#pragma unroll
  for (int ks = 0; ks < 2; ++ks) {
    const int blk = (ks << 2) + lh;
    const int off = (arow << 6) + (((blk ^ arow) & 7) << 3);
    aH[ks] = *(const half8*)&JH[off];
    aL[ks] = *(const half8*)&JL[off];
  }

  float m1[4], l1[4], M2[4];
#pragma unroll
  for (int e = 0; e < 4; ++e) { m1[e] = -1e30f; l1[e] = 0.f; M2[e] = -1e30f; }

  // ---- pass 1: stats + candidates (no global writes) ----
  for (int jt = 0; jt < 32; ++jt) {
    __syncthreads();
    stage_tile(Qh, Ql, JH, JL, qb + ((size_t)jt << 6), tid);
    __syncthreads();
    f32x4 acc[4];
    qk_tile(JH, JL, aH, aL, lw, lh, acc);
#pragma unroll
    for (int e = 0; e < 4; ++e) {
      const int wrow = (w << 4) + (lh << 2) + e;
      const int grow = r0 + wrow;
      const size_t rowb = (qb + grow) * SEQL;
      float s[4], t[4];
#pragma unroll
      for (int ct = 0; ct < 4; ++ct) {
        const int gc = (jt << 6) + (ct << 4) + lw;
        float sv = acc[ct][e];
        if (grow == gc) sv = -1e9f;
        s[ct] = sv;
        t[ct] = sv + gumbelf(U[rowb + gc]);
      }
      // lane-local online log-softmax stats (merged once after the loop)
      const float sm = fmaxf(fmaxf(s[0], s[1]), fmaxf(s[2], s[3]));
      const float nm = fmaxf(m1[e], sm);
      const float es = __expf(s[0] - nm) + __expf(s[1] - nm)
                     + __expf(s[2] - nm) + __expf(s[3] - nm);
      l1[e] = l1[e] * __expf(m1[e] - nm) + es;
      m1[e] = nm;
      // running t-max over this row's cols (wave covers all 64 cols of jt)
      const float tm = bmax16(fmaxf(fmaxf(t[0], t[1]), fmaxf(t[2], t[3])));
      M2[e] = fmaxf(M2[e], tm);
      const float thr = M2[e] - 0.62f;   // exp(x/T)==0 in fp32 for x<-0.588
#pragma unroll
      for (int ct = 0; ct < 4; ++ct)
        if (t[ct] > thr) {
          int z = atomicAdd(&ccnt[wrow], 1);
          if (z < CCAP) cand[wrow][z] = (unsigned short)((jt << 6) + (ct << 4) + lw);
        }
    }
  }
  // ---- merge lane-local stats across the 16 col-lanes (rows are wave-private) ----
  float lse[4];
#pragma unroll
  for (int e = 0; e < 4; ++e) {
#pragma unroll
    for (int d = 1; d < 16; d <<= 1) {
      const float om = __shfl_xor(m1[e], d);
      const float ol = __shfl_xor(l1[e], d);
      const float nm = fmaxf(m1[e], om);
      l1[e] = l1[e] * __expf(m1[e] - nm) + ol * __expf(om - nm);
      m1[e] = nm;
      M2[e] = fmaxf(M2[e], __shfl_xor(M2[e], d));
    }
    lse[e] = m1[e] + __logf(l1[e]);
  }
  __syncthreads();   // candidates from all waves visible

  // ---- candidate gather: att_out = softmax-sample @ V ----
  const int ty = tid >> 4, tx = tid & 15;   // ty == w*4+lh, tx == lw
  const float* Vh = V + (qb << 6);
#pragma unroll 1
  for (int i = 0; i < 4; ++i) {
    const int lr = (ty << 2) + i;
    const int gr = r0 + lr;
    int n = ccnt[lr]; n = (n < CCAP) ? n : CCAP;
    const size_t rowb = (qb + gr) * SEQL;
    const float4 qi = *(const float4*)&Qf[((qb + gr) << 6) + (tx << 2)];
    float l2 = 0.f, ax = 0.f, ay = 0.f, az = 0.f, aw = 0.f;
    for (int c = 0; c < n; ++c) {
      const int j = cand[lr][c];
      const float4 qj = *(const float4*)&Qf[((qb + j) << 6) + (tx << 2)];
      float sd = qi.x*qj.x + qi.y*qj.y + qi.z*qj.z + qi.w*qj.w;
      sd = bsum16(sd);
      if (j == gr) sd = -1e9f;
      const float g = gumbelf(U[rowb + j]);
      const float p = __expf((sd + g - M2[i]) / TEMPF);
      l2 += p;
      const float4 vv = *(const float4*)&Vh[((size_t)j << 6) + (tx << 2)];
      ax += p * vv.x; ay += p * vv.y; az += p * vv.z; aw += p * vv.w;
    }
    const float inv = 1.0f / l2;
    *(float4*)&att[((qb + gr) << 6) + (tx << 2)] =
        make_float4(ax * inv, ay * inv, az * inv, aw * inv);
  }

  // ---- pass 2: recompute QK via MFMA, write logp = s - lse ----
  for (int jt = 0; jt < 32; ++jt) {
    __syncthreads();
    stage_tile(Qh, Ql, JH, JL, qb + ((size_t)jt << 6), tid);
    __syncthreads();
    f32x4 acc[4];
    qk_tile(JH, JL, aH, aL, lw, lh, acc);
#pragma unroll
    for (int e = 0; e < 4; ++e) {
      const int grow = r0 + (w << 4) + (lh << 2) + e;
      const size_t rowb = (qb + grow) * SEQL;
#pragma unroll
      for (int ct = 0; ct < 4; ++ct) {
        const int gc = (jt << 6) + (ct << 4) + lw;
        float sv = acc[ct][e];
        if (grow == gc) sv = -1e9f;
        logp[rowb + gc] = sv - lse[e];
      }
    }
  }
}

// Per-head FF tube (64->128 relu ->64) + pairwise Gumbel-softmax (GS_DIM=2).
__global__ __launch_bounds__(128) void tubes(const float* __restrict__ att,
    const float* __restrict__ ff_w1, const float* __restrict__ ff_b1,
    const float* __restrict__ ff_w2, const float* __restrict__ ff_b2,
    const float* __restrict__ u_gs, float* __restrict__ gs)
{
  __shared__ float w1s[128 * 64];
  __shared__ float w2Ts[128 * 64];
  const int tid = threadIdx.x;
  const int n = blockIdx.x >> 5;
  const int chunk = blockIdx.x & 31;
  const float* w1 = ff_w1 + n * 8192;
  const float* w2 = ff_w2 + n * 8192;
#pragma unroll
  for (int i = 0; i < 16; ++i) {
    const int f = i * 128 + tid;
    ((float4*)w1s)[f] = ((const float4*)w1)[f];
    const int o = f >> 5, j4 = (f & 31) << 2;
    float4 v = ((const float4*)w2)[f];
    w2Ts[(j4 + 0) * 64 + o] = v.x; w2Ts[(j4 + 1) * 64 + o] = v.y;
    w2Ts[(j4 + 2) * 64 + o] = v.z; w2Ts[(j4 + 3) * 64 + o] = v.w;
  }
  __syncthreads();
  const int token = chunk * 128 + tid;
  const int b = token >> 11, s = token & 2047;
  const float* ap = att + (((size_t)(n * NBATCH + b) * SEQL + s) << 6);
  float a[64];
#pragma unroll
  for (int k4 = 0; k4 < 64; k4 += 4) {
    float4 v = *(const float4*)&ap[k4];
    a[k4] = v.x; a[k4 + 1] = v.y; a[k4 + 2] = v.z; a[k4 + 3] = v.w;
  }
  float dm[64] = {};
  for (int j = 0; j < 128; ++j) {
    float h = ff_b1[n * 128 + j];
#pragma unroll
    for (int k4 = 0; k4 < 64; k4 += 4) {
      float4 w = *(const float4*)&w1s[(j << 6) + k4];
      h += w.x * a[k4] + w.y * a[k4 + 1] + w.z * a[k4 + 2] + w.w * a[k4 + 3];
    }
    h = fmaxf(h, 0.f);
#pragma unroll
    for (int o4 = 0; o4 < 64; o4 += 4) {
      float4 w = *(const float4*)&w2Ts[(j << 6) + o4];
      dm[o4] += w.x * h; dm[o4 + 1] += w.y * h; dm[o4 + 2] += w.z * h; dm[o4 + 3] += w.w * h;
    }
  }
  const float* up = u_gs + (((size_t)(n * NBATCH + b) * SEQL + s) << 6);
  float* gp = gs + (((size_t)(b * SEQL + s)) << 9) + (n << 6);
  const float* b2 = ff_b2 + (n << 6);
#pragma unroll
  for (int q = 0; q < 16; ++q) {
    const float4 uu = *(const float4*)&up[q << 2];
    const float d0 = dm[(q << 2) + 0] + b2[(q << 2) + 0];
    const float d1 = dm[(q << 2) + 1] + b2[(q << 2) + 1];
    const float d2 = dm[(q << 2) + 2] + b2[(q << 2) + 2];
    const float d3 = dm[(q << 2) + 3] + b2[(q << 2) + 3];
    const float z0 = d0 + gumbelf(uu.x), z1 = d1 + gumbelf(uu.y);
    const float z2 = d2 + gumbelf(uu.z), z3 = d3 + gumbelf(uu.w);
    const float ma = fmaxf(z0, z1), mb = fmaxf(z2, z3);
    const float e0 = __expf((z0 - ma) / TEMPF), e1 = __expf((z1 - ma) / TEMPF);
    const float e2 = __expf((z2 - mb) / TEMPF), e3 = __expf((z3 - mb) / TEMPF);
    const float ia = 1.0f / (e0 + e1), ib = 1.0f / (e2 + e3);
    *(float4*)&gp[q << 2] = make_float4(e0 * ia, e1 * ia, e2 * ib, e3 * ib);
  }
}

extern "C" void kernel_launch(void* const* d_in, const int* in_sizes, int n_in,
                              void* d_out, int out_size, void* d_ws, size_t ws_size,
                              hipStream_t stream) {
  const float* kq    = (const float*)d_in[0];
  const float* v     = (const float*)d_in[1];
  const float* w_kq  = (const float*)d_in[2];
  const float* b_kq  = (const float*)d_in[3];
  const float* w_v   = (const float*)d_in[4];
  const float* b_v   = (const float*)d_in[5];
  const float* ff_w1 = (const float*)d_in[6];
  const float* ff_b1 = (const float*)d_in[7];
  const float* ff_w2 = (const float*)d_in[8];
  const float* ff_b2 = (const float*)d_in[9];
  const float* fc_w  = (const float*)d_in[10];
  const float* fc_b  = (const float*)d_in[11];
  const float* u_at  = (const float*)d_in[12];
  const float* u_gs  = (const float*)d_in[13];
  float* out  = (float*)d_out;
  float* logp = out + (size_t)NBATCH * SEQL * 512;
  float* ws   = (float*)d_ws;
  float* Q    = ws;
  float* V    = Q + (size_t)BHN * SEQL * 64;
  float* att  = V + (size_t)BHN * SEQL * 64;
  float* gs   = att + (size_t)BHN * SEQL * 64;
  // fp16 hi/lo split of Q aliases the gs region (gs written only later by tubes)
  _Float16* Qh16 = (_Float16*)gs;
  _Float16* Ql16 = Qh16 + (size_t)BHN * SEQL * 64;

  gemm512<<<512, 256, 0, stream>>>(kq, w_kq, b_kq, Q, 1);
  gemm512<<<512, 256, 0, stream>>>(v, w_v, b_v, V, 1);
  qsplit<<<2048, 256, 0, stream>>>(Q, Qh16, Ql16);
  attn_fused<<<512, 256, 0, stream>>>(Q, Qh16, Ql16, V, u_at, logp, att);
  tubes<<<256, 128, 0, stream>>>(att, ff_w1, ff_b1, ff_w2, ff_b2, u_gs, gs);
  gemm512<<<512, 256, 0, stream>>>(gs, fc_w, fc_b, out, 0);
}

// Round 2
// 722.029 us; speedup vs baseline: 1.4695x; 1.2655x over previous
//
#include <hip/hip_runtime.h>

// MultiHeadAttention_Discrete — round 4.
// gemm512 -> MFMA (fp16 hi/lo split, inline conversion, 32x64 tiles, 1024 blocks).
//   Q-gemm also emits Qh/Ql fp16 halves directly (qsplit kernel deleted).
// tubes   -> MFMA (two chained per-head GEMMs, LDS round-trip for relu'd hidden).
// attn    -> unchanged from round-3 (validated).
// ws layout (floats): Q[16*2048*64] | V[16*2048*64] | att[16*2048*64] | gs[2*2048*512]
// Qh/Ql (fp16, 4MB each) alias the gs region (gs written later by tubes).

#define NHEAD 8
#define NBATCH 2
#define SEQL 2048
#define BHN 16
#define TEMPF 0.006737946999085467f
#define CCAP 128

typedef __attribute__((ext_vector_type(8))) _Float16 half8;
typedef __attribute__((ext_vector_type(4))) float f32x4;

__device__ __forceinline__ float gumbelf(float u) {
  return -__logf(-__logf(u + 1e-10f) + 1e-10f);
}
__device__ __forceinline__ float bmax16(float v) {
  v = fmaxf(v, __shfl_xor(v, 1));
  v = fmaxf(v, __shfl_xor(v, 2));
  v = fmaxf(v, __shfl_xor(v, 4));
  v = fmaxf(v, __shfl_xor(v, 8));
  return v;
}
__device__ __forceinline__ float bsum16(float v) {
  v += __shfl_xor(v, 1);
  v += __shfl_xor(v, 2);
  v += __shfl_xor(v, 4);
  v += __shfl_xor(v, 8);
  return v;
}
// fp32x8 -> fp16 hi + fp16 lo (x = hi + lo to ~2^-22 rel).
__device__ __forceinline__ void cvt8(const float4 a, const float4 b, half8& h, half8& l) {
  h[0] = (_Float16)a.x; h[1] = (_Float16)a.y; h[2] = (_Float16)a.z; h[3] = (_Float16)a.w;
  h[4] = (_Float16)b.x; h[5] = (_Float16)b.y; h[6] = (_Float16)b.z; h[7] = (_Float16)b.w;
  l[0] = (_Float16)(a.x - (float)h[0]); l[1] = (_Float16)(a.y - (float)h[1]);
  l[2] = (_Float16)(a.z - (float)h[2]); l[3] = (_Float16)(a.w - (float)h[3]);
  l[4] = (_Float16)(b.x - (float)h[4]); l[5] = (_Float16)(b.y - (float)h[5]);
  l[6] = (_Float16)(b.z - (float)h[6]); l[7] = (_Float16)(b.w - (float)h[7]);
}

// Y[m][c] = sum_k X[m][k]*W[c][k] + bias[c];  M=4096, N=512, K=512.
// MFMA fp16-split version. 32x64 tile, 1024 blocks, 4 waves (2 row-grp x 2 col-half).
// If Qh16 != null (headsplit Q gemm): also emit fp16 hi/lo of Y.
__global__ __launch_bounds__(256, 4) void gemm512_mfma(const float* __restrict__ X,
    const float* __restrict__ W, const float* __restrict__ bias,
    float* __restrict__ Y, int headsplit,
    _Float16* __restrict__ Qh16, _Float16* __restrict__ Ql16)
{
  __shared__ __align__(16) _Float16 XH[2048];   // [32][64]
  __shared__ __align__(16) _Float16 XL[2048];
  __shared__ __align__(16) _Float16 WH[4096];   // [64][64]
  __shared__ __align__(16) _Float16 WL[4096];
  const int tid = threadIdx.x;
  const int w = tid >> 6, l = tid & 63, lw = l & 15, lh = l >> 4;
  const int rg = w & 1, ch = w >> 1;
  const int mt = blockIdx.x >> 3, nt = blockIdx.x & 7;
  const int m0 = mt << 5, n0 = nt << 6;
  const int arow = (rg << 4) + lw;
  f32x4 acc[2];
  acc[0] = (f32x4){0.f, 0.f, 0.f, 0.f};
  acc[1] = (f32x4){0.f, 0.f, 0.f, 0.f};
  for (int kc = 0; kc < 8; ++kc) {
    if (kc) __syncthreads();
    {  // stage X chunk: 32 rows x 64 k
      const int srow = tid >> 3, sblk = tid & 7;
      const float* xp = X + (size_t)(m0 + srow) * 512 + (kc << 6) + (sblk << 3);
      float4 x0 = *(const float4*)xp;
      float4 x1 = *(const float4*)(xp + 4);
      half8 h, lo; cvt8(x0, x1, h, lo);
      const int dst = (srow << 6) + (((sblk ^ srow) & 7) << 3);
      *(half8*)&XH[dst] = h; *(half8*)&XL[dst] = lo;
    }
#pragma unroll
    for (int p = 0; p < 2; ++p) {  // stage W chunk: 64 rows x 64 k
      const int idx = (p << 8) + tid;
      const int srow = idx >> 3, sblk = idx & 7;
      const float* wp = W + (size_t)(n0 + srow) * 512 + (kc << 6) + (sblk << 3);
      float4 x0 = *(const float4*)wp;
      float4 x1 = *(const float4*)(wp + 4);
      half8 h, lo; cvt8(x0, x1, h, lo);
      const int dst = (srow << 6) + (((sblk ^ srow) & 7) << 3);
      *(half8*)&WH[dst] = h; *(half8*)&WL[dst] = lo;
    }
    __syncthreads();
#pragma unroll
    for (int ks = 0; ks < 2; ++ks) {
      const int blk = (ks << 2) + lh;
      const int aoff = (arow << 6) + (((blk ^ arow) & 7) << 3);
      const half8 aH = *(const half8*)&XH[aoff];
      const half8 aL = *(const half8*)&XL[aoff];
#pragma unroll
      for (int j = 0; j < 2; ++j) {
        const int brow = (((ch << 1) + j) << 4) + lw;
        const int boff = (brow << 6) + (((blk ^ brow) & 7) << 3);
        const half8 bH = *(const half8*)&WH[boff];
        const half8 bL = *(const half8*)&WL[boff];
        acc[j] = __builtin_amdgcn_mfma_f32_16x16x32_f16(aH, bH, acc[j], 0, 0, 0);
        acc[j] = __builtin_amdgcn_mfma_f32_16x16x32_f16(aH, bL, acc[j], 0, 0, 0);
        acc[j] = __builtin_amdgcn_mfma_f32_16x16x32_f16(aL, bH, acc[j], 0, 0, 0);
      }
    }
  }
#pragma unroll
  for (int j = 0; j < 2; ++j) {
    const int cl = (((ch << 1) + j) << 4) + lw;  // 0..63 within tile
    const float bv = bias[n0 + cl];
#pragma unroll
    for (int e = 0; e < 4; ++e) {
      const int m = m0 + (rg << 4) + (lh << 2) + e;
      const float val = acc[j][e] + bv;
      if (headsplit) {
        const int bb = m >> 11, s = m & 2047;
        const size_t oi = (((size_t)(nt * NBATCH + bb) * SEQL + s) << 6) + cl;
        Y[oi] = val;
        if (Qh16) {
          const _Float16 hv = (_Float16)val;
          Qh16[oi] = hv; Ql16[oi] = (_Float16)(val - (float)hv);
        }
      } else {
        Y[((size_t)m << 9) + n0 + cl] = val;
      }
    }
  }
}

// Stage a 64-row x 64-col fp16 hi/lo tile into LDS with 16B-block XOR swizzle.
__device__ __forceinline__ void stage_tile(const _Float16* __restrict__ Qh,
    const _Float16* __restrict__ Ql, _Float16* JH, _Float16* JL,
    size_t qrow0, int tid)
{
#pragma unroll
  for (int r = 0; r < 2; ++r) {
    const int idx = (r << 8) + tid;
    const int srow = idx >> 3, sblk = idx & 7;
    const int dst = (srow << 6) + (((sblk ^ srow) & 7) << 3);
    const size_t src = ((qrow0 + srow) << 6) + (sblk << 3);
    *(float4*)&JH[dst] = *(const float4*)&Qh[src];
    *(float4*)&JL[dst] = *(const float4*)&Ql[src];
  }
}

// 16 rows (this wave) x 64 cols QK^T tile via fp16x2-split MFMA.
__device__ __forceinline__ void qk_tile(const _Float16* JH, const _Float16* JL,
    const half8 aH[2], const half8 aL[2], int lw, int lh, f32x4 acc[4])
{
#pragma unroll
  for (int ct = 0; ct < 4; ++ct) acc[ct] = (f32x4){0.f, 0.f, 0.f, 0.f};
#pragma unroll
  for (int ks = 0; ks < 2; ++ks) {
    half8 bh8[4], bl8[4];
#pragma unroll
    for (int ct = 0; ct < 4; ++ct) {
      const int jrow = (ct << 4) + lw;
      const int blk = (ks << 2) + lh;
      const int off = (jrow << 6) + (((blk ^ jrow) & 7) << 3);
      bh8[ct] = *(const half8*)&JH[off];
      bl8[ct] = *(const half8*)&JL[off];
    }
#pragma unroll
    for (int ct = 0; ct < 4; ++ct)
      acc[ct] = __builtin_amdgcn_mfma_f32_16x16x32_f16(aH[ks], bh8[ct], acc[ct], 0, 0, 0);
#pragma unroll
    for (int ct = 0; ct < 4; ++ct)
      acc[ct] = __builtin_amdgcn_mfma_f32_16x16x32_f16(aH[ks], bl8[ct], acc[ct], 0, 0, 0);
#pragma unroll
    for (int ct = 0; ct < 4; ++ct)
      acc[ct] = __builtin_amdgcn_mfma_f32_16x16x32_f16(aL[ks], bh8[ct], acc[ct], 0, 0, 0);
  }
}

// Fused attention (round-3 version, unchanged).
__global__ __launch_bounds__(256) void attn_fused(const float* __restrict__ Qf,
    const _Float16* __restrict__ Qh, const _Float16* __restrict__ Ql,
    const float* __restrict__ V, const float* __restrict__ U,
    float* __restrict__ logp, float* __restrict__ att)
{
  __shared__ __align__(16) _Float16 JH[4096];
  __shared__ __align__(16) _Float16 JL[4096];
  __shared__ unsigned short cand[64][CCAP];
  __shared__ int ccnt[64];
  const int tid = threadIdx.x;
  const int w = tid >> 6;
  const int l = tid & 63;
  const int lw = l & 15, lh = l >> 4;
  const int bh = ((blockIdx.x & 7) << 1) | ((blockIdx.x >> 3) & 1);
  const int rb = blockIdx.x >> 4;
  const int r0 = rb << 6;
  const size_t qb = (size_t)bh * SEQL;
  if (tid < 64) ccnt[tid] = 0;

  stage_tile(Qh, Ql, JH, JL, qb + r0, tid);
  __syncthreads();
  half8 aH[2], aL[2];
  const int arow = (w << 4) + lw;
#pragma unroll
  for (int ks = 0; ks < 2; ++ks) {
    const int blk = (ks << 2) + lh;
    const int off = (arow << 6) + (((blk ^ arow) & 7) << 3);
    aH[ks] = *(const half8*)&JH[off];
    aL[ks] = *(const half8*)&JL[off];
  }

  float m1[4], l1[4], M2[4];
#pragma unroll
  for (int e = 0; e < 4; ++e) { m1[e] = -1e30f; l1[e] = 0.f; M2[e] = -1e30f; }

  // ---- pass 1: stats + candidates (no global writes) ----
  for (int jt = 0; jt < 32; ++jt) {
    __syncthreads();
    stage_tile(Qh, Ql, JH, JL, qb + ((size_t)jt << 6), tid);
    __syncthreads();
    f32x4 acc[4];
    qk_tile(JH, JL, aH, aL, lw, lh, acc);
#pragma unroll
    for (int e = 0; e < 4; ++e) {
      const int wrow = (w << 4) + (lh << 2) + e;
      const int grow = r0 + wrow;
      const size_t rowb = (qb + grow) * SEQL;
      float s[4], t[4];
#pragma unroll
      for (int ct = 0; ct < 4; ++ct) {
        const int gc = (jt << 6) + (ct << 4) + lw;
        float sv = acc[ct][e];
        if (grow == gc) sv = -1e9f;
        s[ct] = sv;
        t[ct] = sv + gumbelf(U[rowb + gc]);
      }
      const float sm = fmaxf(fmaxf(s[0], s[1]), fmaxf(s[2], s[3]));
      const float nm = fmaxf(m1[e], sm);
      const float es = __expf(s[0] - nm) + __expf(s[1] - nm)
                     + __expf(s[2] - nm) + __expf(s[3] - nm);
      l1[e] = l1[e] * __expf(m1[e] - nm) + es;
      m1[e] = nm;
      const float tm = bmax16(fmaxf(fmaxf(t[0], t[1]), fmaxf(t[2], t[3])));
      M2[e] = fmaxf(M2[e], tm);
      const float thr = M2[e] - 0.62f;   // exp(x/T)==0 in fp32 for x<-0.588
#pragma unroll
      for (int ct = 0; ct < 4; ++ct)
        if (t[ct] > thr) {
          int z = atomicAdd(&ccnt[wrow], 1);
          if (z < CCAP) cand[wrow][z] = (unsigned short)((jt << 6) + (ct << 4) + lw);
        }
    }
  }
  // ---- merge lane-local stats across the 16 col-lanes ----
  float lse[4];
#pragma unroll
  for (int e = 0; e < 4; ++e) {
#pragma unroll
    for (int d = 1; d < 16; d <<= 1) {
      const float om = __shfl_xor(m1[e], d);
      const float ol = __shfl_xor(l1[e], d);
      const float nm = fmaxf(m1[e], om);
      l1[e] = l1[e] * __expf(m1[e] - nm) + ol * __expf(om - nm);
      m1[e] = nm;
      M2[e] = fmaxf(M2[e], __shfl_xor(M2[e], d));
    }
    lse[e] = m1[e] + __logf(l1[e]);
  }
  __syncthreads();

  // ---- candidate gather: att_out = softmax-sample @ V ----
  const int ty = tid >> 4, tx = tid & 15;
  const float* Vh = V + (qb << 6);
#pragma unroll 1
  for (int i = 0; i < 4; ++i) {
    const int lr = (ty << 2) + i;
    const int gr = r0 + lr;
    int n = ccnt[lr]; n = (n < CCAP) ? n : CCAP;
    const size_t rowb = (qb + gr) * SEQL;
    const float4 qi = *(const float4*)&Qf[((qb + gr) << 6) + (tx << 2)];
    float l2 = 0.f, ax = 0.f, ay = 0.f, az = 0.f, aw = 0.f;
    for (int c = 0; c < n; ++c) {
      const int j = cand[lr][c];
      const float4 qj = *(const float4*)&Qf[((qb + j) << 6) + (tx << 2)];
      float sd = qi.x*qj.x + qi.y*qj.y + qi.z*qj.z + qi.w*qj.w;
      sd = bsum16(sd);
      if (j == gr) sd = -1e9f;
      const float g = gumbelf(U[rowb + j]);
      const float p = __expf((sd + g - M2[i]) / TEMPF);
      l2 += p;
      const float4 vv = *(const float4*)&Vh[((size_t)j << 6) + (tx << 2)];
      ax += p * vv.x; ay += p * vv.y; az += p * vv.z; aw += p * vv.w;
    }
    const float inv = 1.0f / l2;
    *(float4*)&att[((qb + gr) << 6) + (tx << 2)] =
        make_float4(ax * inv, ay * inv, az * inv, aw * inv);
  }

  // ---- pass 2: recompute QK via MFMA, write logp = s - lse ----
  for (int jt = 0; jt < 32; ++jt) {
    __syncthreads();
    stage_tile(Qh, Ql, JH, JL, qb + ((size_t)jt << 6), tid);
    __syncthreads();
    f32x4 acc[4];
    qk_tile(JH, JL, aH, aL, lw, lh, acc);
#pragma unroll
    for (int e = 0; e < 4; ++e) {
      const int grow = r0 + (w << 4) + (lh << 2) + e;
      const size_t rowb = (qb + grow) * SEQL;
#pragma unroll
      for (int ct = 0; ct < 4; ++ct) {
        const int gc = (jt << 6) + (ct << 4) + lw;
        float sv = acc[ct][e];
        if (grow == gc) sv = -1e9f;
        logp[rowb + gc] = sv - lse[e];
      }
    }
  }
}

// Per-head FF tube (64->128 relu ->64) via MFMA + pairwise Gumbel-softmax.
// One block = one head x 64 tokens. LDS union (64 KB):
//   phase1: AH[0,8K) AL[8K..) att 64x64 ; W1H/W1L [8K..24K) 128x64  (byte offsets x2)
//   phase2: HH/HL [0,32K) 64x128 ; W2H/W2L [32K,64K) 64x128
__global__ __launch_bounds__(256, 2) void tubes_mfma(const float* __restrict__ att,
    const float* __restrict__ ff_w1, const float* __restrict__ ff_b1,
    const float* __restrict__ ff_w2, const float* __restrict__ ff_b2,
    const float* __restrict__ u_gs, float* __restrict__ gs)
{
  __shared__ __align__(16) _Float16 L[32768];   // 64 KB
  _Float16* AH  = L;             // [64][64]
  _Float16* AL  = L + 4096;
  _Float16* W1H = L + 8192;      // [128][64]
  _Float16* W1L = L + 16384;
  _Float16* HH  = L;             // [64][128]
  _Float16* HL  = L + 8192;
  _Float16* W2H = L + 16384;     // [64][128]
  _Float16* W2L = L + 24576;
  const int tid = threadIdx.x;
  const int w = tid >> 6, l = tid & 63, lw = l & 15, lh = l >> 4;
  const int n = blockIdx.x >> 6;
  const int t0 = (blockIdx.x & 63) << 6;
  const int arow = (w << 4) + lw;

  // stage att tile (64 tokens x 64, fp32 -> fp16 hi/lo)
#pragma unroll
  for (int p = 0; p < 2; ++p) {
    const int idx = (p << 8) + tid;
    const int srow = idx >> 3, sblk = idx & 7;
    const int tok = t0 + srow;
    const int b = tok >> 11, s = tok & 2047;
    const float* ap = att + (((size_t)(n * NBATCH + b) * SEQL + s) << 6) + (sblk << 3);
    float4 x0 = *(const float4*)ap;
    float4 x1 = *(const float4*)(ap + 4);
    half8 h, lo; cvt8(x0, x1, h, lo);
    const int dst = (srow << 6) + (((sblk ^ srow) & 7) << 3);
    *(half8*)&AH[dst] = h; *(half8*)&AL[dst] = lo;
  }
  // stage W1 (128 x 64)
#pragma unroll
  for (int p = 0; p < 4; ++p) {
    const int idx = (p << 8) + tid;
    const int srow = idx >> 3, sblk = idx & 7;
    const float* wp = ff_w1 + n * 8192 + (srow << 6) + (sblk << 3);
    float4 x0 = *(const float4*)wp;
    float4 x1 = *(const float4*)(wp + 4);
    half8 h, lo; cvt8(x0, x1, h, lo);
    const int dst = (srow << 6) + (((sblk ^ srow) & 7) << 3);
    *(half8*)&W1H[dst] = h; *(half8*)&W1L[dst] = lo;
  }
  float b1v[8];
#pragma unroll
  for (int ct = 0; ct < 8; ++ct) b1v[ct] = ff_b1[(n << 7) + (ct << 4) + lw];
  __syncthreads();

  // phase 1: H = relu(att @ W1^T + b1), 16 tokens x 128 hidden per wave
  f32x4 acc1[8];
#pragma unroll
  for (int ct = 0; ct < 8; ++ct) acc1[ct] = (f32x4){0.f, 0.f, 0.f, 0.f};
#pragma unroll
  for (int ks = 0; ks < 2; ++ks) {
    const int blk = (ks << 2) + lh;
    const int aoff = (arow << 6) + (((blk ^ arow) & 7) << 3);
    const half8 aH = *(const half8*)&AH[aoff];
    const half8 aL = *(const half8*)&AL[aoff];
#pragma unroll
    for (int ct = 0; ct < 8; ++ct) {
      const int brow = (ct << 4) + lw;
      const int boff = (brow << 6) + (((blk ^ brow) & 7) << 3);
      const half8 bH = *(const half8*)&W1H[boff];
      const half8 bL = *(const half8*)&W1L[boff];
      acc1[ct] = __builtin_amdgcn_mfma_f32_16x16x32_f16(aH, bH, acc1[ct], 0, 0, 0);
      acc1[ct] = __builtin_amdgcn_mfma_f32_16x16x32_f16(aH, bL, acc1[ct], 0, 0, 0);
      acc1[ct] = __builtin_amdgcn_mfma_f32_16x16x32_f16(aL, bH, acc1[ct], 0, 0, 0);
    }
  }
  __syncthreads();   // all phase-1 LDS reads done -> safe to overwrite

  // relu + bias, write H hi/lo into HH/HL (swizzled [64][128])
#pragma unroll
  for (int ct = 0; ct < 8; ++ct) {
#pragma unroll
    for (int e = 0; e < 4; ++e) {
      const int hrow = (w << 4) + (lh << 2) + e;
      const int col = (ct << 4) + lw;
      const float h = fmaxf(acc1[ct][e] + b1v[ct], 0.f);
      const _Float16 hh = (_Float16)h;
      const _Float16 hl = (_Float16)(h - (float)hh);
      const int cb = col >> 3;
      const int off = (hrow << 7) + (((cb & 8) | ((cb ^ hrow) & 7)) << 3) + (col & 7);
      HH[off] = hh; HL[off] = hl;
    }
  }
  // stage W2 (64 x 128)
#pragma unroll
  for (int p = 0; p < 4; ++p) {
    const int idx = (p << 8) + tid;
    const int srow = idx >> 4, sblk = idx & 15;
    const float* wp = ff_w2 + n * 8192 + (srow << 7) + (sblk << 3);
    float4 x0 = *(const float4*)wp;
    float4 x1 = *(const float4*)(wp + 4);
    half8 h, lo; cvt8(x0, x1, h, lo);
    const int dst = (srow << 7) + (((sblk & 8) | ((sblk ^ srow) & 7)) << 3);
    *(half8*)&W2H[dst] = h; *(half8*)&W2L[dst] = lo;
  }
  float b2v[4];
#pragma unroll
  for (int ct = 0; ct < 4; ++ct) b2v[ct] = ff_b2[(n << 6) + (ct << 4) + lw];
  __syncthreads();

  // phase 2: D = H @ W2^T, 16 tokens x 64 out per wave
  f32x4 acc2[4];
#pragma unroll
  for (int ct = 0; ct < 4; ++ct) acc2[ct] = (f32x4){0.f, 0.f, 0.f, 0.f};
#pragma unroll
  for (int ks = 0; ks < 4; ++ks) {
    const int blk = (ks << 2) + lh;   // 0..15
    const int aoff = (arow << 7) + (((blk & 8) | ((blk ^ arow) & 7)) << 3);
    const half8 aH = *(const half8*)&HH[aoff];
    const half8 aL = *(const half8*)&HL[aoff];
#pragma unroll
    for (int ct = 0; ct < 4; ++ct) {
      const int brow = (ct << 4) + lw;
      const int boff = (brow << 7) + (((blk & 8) | ((blk ^ brow) & 7)) << 3);
      const half8 bH = *(const half8*)&W2H[boff];
      const half8 bL = *(const half8*)&W2L[boff];
      acc2[ct] = __builtin_amdgcn_mfma_f32_16x16x32_f16(aH, bH, acc2[ct], 0, 0, 0);
      acc2[ct] = __builtin_amdgcn_mfma_f32_16x16x32_f16(aH, bL, acc2[ct], 0, 0, 0);
      acc2[ct] = __builtin_amdgcn_mfma_f32_16x16x32_f16(aL, bH, acc2[ct], 0, 0, 0);
    }
  }
  // epilogue: pairwise Gumbel-softmax over (o, o^1) via shfl_xor(1)
#pragma unroll
  for (int ct = 0; ct < 4; ++ct) {
#pragma unroll
    for (int e = 0; e < 4; ++e) {
      const int tok = t0 + (w << 4) + (lh << 2) + e;
      const int b = tok >> 11, s = tok & 2047;
      const int o = (ct << 4) + lw;
      const float d = acc2[ct][e] + b2v[ct];
      const float u = u_gs[(((size_t)(n * NBATCH + b) * SEQL + s) << 6) + o];
      const float z = d + gumbelf(u);
      const float zp = __shfl_xor(z, 1);
      const float m = fmaxf(z, zp);
      const float e0 = __expf((z - m) / TEMPF);
      const float e1 = __expf((zp - m) / TEMPF);
      gs[(((size_t)(b * SEQL + s)) << 9) + (n << 6) + o] = e0 / (e0 + e1);
    }
  }
}

extern "C" void kernel_launch(void* const* d_in, const int* in_sizes, int n_in,
                              void* d_out, int out_size, void* d_ws, size_t ws_size,
                              hipStream_t stream) {
  const float* kq    = (const float*)d_in[0];
  const float* v     = (const float*)d_in[1];
  const float* w_kq  = (const float*)d_in[2];
  const float* b_kq  = (const float*)d_in[3];
  const float* w_v   = (const float*)d_in[4];
  const float* b_v   = (const float*)d_in[5];
  const float* ff_w1 = (const float*)d_in[6];
  const float* ff_b1 = (const float*)d_in[7];
  const float* ff_w2 = (const float*)d_in[8];
  const float* ff_b2 = (const float*)d_in[9];
  const float* fc_w  = (const float*)d_in[10];
  const float* fc_b  = (const float*)d_in[11];
  const float* u_at  = (const float*)d_in[12];
  const float* u_gs  = (const float*)d_in[13];
  float* out  = (float*)d_out;
  float* logp = out + (size_t)NBATCH * SEQL * 512;
  float* ws   = (float*)d_ws;
  float* Q    = ws;
  float* V    = Q + (size_t)BHN * SEQL * 64;
  float* att  = V + (size_t)BHN * SEQL * 64;
  float* gs   = att + (size_t)BHN * SEQL * 64;
  // fp16 hi/lo split of Q aliases the gs region (gs written only later by tubes)
  _Float16* Qh16 = (_Float16*)gs;
  _Float16* Ql16 = Qh16 + (size_t)BHN * SEQL * 64;

  gemm512_mfma<<<1024, 256, 0, stream>>>(kq, w_kq, b_kq, Q, 1, Qh16, Ql16);
  gemm512_mfma<<<1024, 256, 0, stream>>>(v, w_v, b_v, V, 1, nullptr, nullptr);
  attn_fused<<<512, 256, 0, stream>>>(Q, Qh16, Ql16, V, u_at, logp, att);
  tubes_mfma<<<512, 256, 0, stream>>>(att, ff_w1, ff_b1, ff_w2, ff_b2, u_gs, gs);
  gemm512_mfma<<<1024, 256, 0, stream>>>(gs, fc_w, fc_b, out, 0, nullptr, nullptr);
}